// Round 6
// baseline (136.959 us; speedup 1.0000x reference)
//
#include <hip/hip_runtime.h>
#include <hip/hip_bf16.h>
#include <math.h>

// Problem constants (fixed by setup_inputs): B=4, C=1, H=W=256 -> N=65536/row,
// concat doubles batch to 8 rows. bins = linspace(0,255,256) -> bins[i] == i
// exactly in f32. Values are uniform[0,1)*1275.
//
// exp(-0.5*((v-i)/0.32)^2) underflows f32 to exactly 0.0 for |v-i| > ~4.61,
// so a radius-5 window is numerically identical to the dense reference
// (verified: absmax == 0.0 in round 4).
//
// Joint entropy via H = log2(S')*(S/S') - (sum v*log2 v)/S', S' = S + EPS
// (also verified exact in round 4).
//
// Round-5/6 change (from measured counters: VALUBusy 25%, Occupancy 26%,
// HBM 1.4% -> stall/imbalance-bound): 256-thread blocks, sample-chunked
// grid of 1600 near-equal blocks (~6.25/CU, up to 8 blocks/CU resident),
// partial joint tiles merged into global joint[8][256][256] with device
// atomics; wave-uniform readlane instead of ds_bpermute in the event loop.
#define NB     256
#define NSAMP  65536
#define NROWS  8
#define RADIUS 5.0f
#define EPSV   1e-10f

#define JW     8          // joint j-tile width
#define NJT    32         // j tiles (32*8 = 256)
#define NC_LO  4          // sample chunks per (b<4, jt) tile   (16384 each)
#define NC_HI  8          // sample chunks per (b>=4, jt) tile  (8192 each)
#define NHCH   8          // hist chunks per row (8192 each)

#define NBLK_LO   (4 * NJT * NC_LO)     // 512
#define NBLK_HI   (4 * NJT * NC_HI)     // 1024
#define NBLK_HIST (NROWS * NHCH)        // 64
#define NBLK_ALL  (NBLK_LO + NBLK_HI + NBLK_HIST)   // 1600

// exp(-0.5*(d/0.32)^2) = exp2(EC * d * d), EC = -0.5*log2(e)/0.1024
#define EC     (-7.0444093793406415f)

static __device__ __forceinline__ float scale_val(float x) {
    return x * 255.0f * 5.0f;   // match reference assoc: (x*255)*5
}
static __device__ __forceinline__ float gkern(float d) {
    return exp2f(EC * d * d);
}
static __device__ __forceinline__ float comp4(const float4& v, int e) {
    return e == 0 ? v.x : e == 1 ? v.y : e == 2 ? v.z : v.w;
}
static __device__ __forceinline__ float bcast_lane(float v, int src) {
    // src is wave-uniform (from ffsll of a ballot) -> v_readlane, no LDS trip
    return __int_as_float(__builtin_amdgcn_readlane(__float_as_int(v), src));
}

// ---------------------------------------------------------------------------
// Flat grid of 1600 blocks x 256 threads:
//   [0, 512)        : b<4 joint tiles, 4 chunks each (scan s1+s2)
//   [512, 1536)     : b>=4 joint tiles, 8 chunks each (scan s2 only)
//   [1536, 1600)    : histogram rows, 8 chunks each
__global__ __launch_bounds__(256, 8)
void mi_main_kernel(const float* __restrict__ in1,
                    const float* __restrict__ in2,
                    float* __restrict__ hist,    // [8][256], pre-zeroed
                    float* __restrict__ joint) { // [8][256][256], pre-zeroed
    const int blk  = blockIdx.x;
    const int tid  = threadIdx.x;          // 0..255
    const int lane = tid & 63;

    if (blk >= NBLK_LO + NBLK_HI) {
        // ---------------- histogram role ----------------------------------
        const int idx = blk - (NBLK_LO + NBLK_HI);
        const int row = idx >> 3;          // 0..7
        const int ch  = idx & 7;           // 0..7
        __shared__ float sh[NB];
        sh[tid] = 0.0f;
        __syncthreads();
        const float* src = (row < 4) ? (in1 + row * NSAMP)
                                     : (in2 + (row - 4) * NSAMP);
        const float4* s4 =
            reinterpret_cast<const float4*>(src + ch * (NSAMP / NHCH));
        #pragma unroll
        for (int k = 0; k < (NSAMP / NHCH) / (256 * 4); ++k) {   // 8 iters
            float4 v4 = s4[k * 256 + tid];
            #pragma unroll
            for (int e = 0; e < 4; ++e) {
                float v = scale_val(comp4(v4, e));
                if (v <= 255.0f + RADIUS) {
                    int i0 = (int)ceilf(v - RADIUS);  if (i0 < 0)   i0 = 0;
                    int i1 = (int)floorf(v + RADIUS); if (i1 > 255) i1 = 255;
                    for (int i = i0; i <= i1; ++i)
                        __hip_atomic_fetch_add(&sh[i], gkern(v - (float)i),
                                               __ATOMIC_RELAXED,
                                               __HIP_MEMORY_SCOPE_WORKGROUP);
                }
            }
        }
        __syncthreads();
        __hip_atomic_fetch_add(&hist[row * NB + tid], sh[tid],
                               __ATOMIC_RELAXED, __HIP_MEMORY_SCOPE_AGENT);
        return;
    }

    // ---------------- joint role ------------------------------------------
    int b, jt, ch, nsm;
    if (blk < NBLK_LO) {
        b   = blk / (NJT * NC_LO);
        int q = blk % (NJT * NC_LO);
        jt  = q / NC_LO;
        ch  = q % NC_LO;
        nsm = NSAMP / NC_LO;               // 16384
    } else {
        int i2 = blk - NBLK_LO;
        b   = 4 + i2 / (NJT * NC_HI);
        int q = i2 % (NJT * NC_HI);
        jt  = q / NC_HI;
        ch  = q % NC_HI;
        nsm = NSAMP / NC_HI;               // 8192
    }
    const int base = ch * nsm;

    __shared__ float tile[NB][JW];         // 8 KiB partial tile
    float* tf = &tile[0][0];
    #pragma unroll
    for (int k = 0; k < NB * JW / 256; ++k)                     // 8 iters
        tf[k * 256 + tid] = 0.0f;
    __syncthreads();

    const float* s2 = in2 + (b & 3) * NSAMP;
    const float* s1 = (b < 4) ? (in1 + b * NSAMP) : s2;

    const int   j0    = jt * JW;
    const float jlof  = (float)j0 - RADIUS;
    const float jhif  = (float)(j0 + JW - 1) + RADIUS;
    const float v1max = 255.0f + RADIUS;
    const int   u = lane & 7;              // j offset within stamp
    const int   r = lane >> 3;             // i offset within stamp

    const float4* s24 = reinterpret_cast<const float4*>(s2 + base);
    const float4* s14 = reinterpret_cast<const float4*>(s1 + base);
    const int iters = nsm / (256 * 4);     // lo: 16, hi: 8

    for (int k = 0; k < iters; ++k) {
        float4 c2 = s24[k * 256 + tid];
        float4 c1 = (b < 4) ? s14[k * 256 + tid] : c2;
        #pragma unroll
        for (int e = 0; e < 4; ++e) {
            float v2 = scale_val(comp4(c2, e));
            float v1 = scale_val(comp4(c1, e));
            bool pass = (v2 >= jlof) & (v2 <= jhif) & (v1 <= v1max);
            unsigned long long m = __ballot(pass);
            while (m) {                    // one whole-wave stamp per event
                int src = __ffsll(m) - 1;
                m &= m - 1;
                float w1 = bcast_lane(v1, src);
                float w2 = bcast_lane(v2, src);
                int jlo = (int)ceilf(w2 - RADIUS);  if (jlo < j0)          jlo = j0;
                int jhi = (int)floorf(w2 + RADIUS); if (jhi > j0 + JW - 1) jhi = j0 + JW - 1;
                int ilo = (int)ceilf(w1 - RADIUS);  if (ilo < 0)   ilo = 0;
                int ihi = (int)floorf(w1 + RADIUS); if (ihi > 255) ihi = 255;
                int j = jlo + u;
                bool jok = (j <= jhi);
                float ej = gkern(w2 - (float)j);   // register-only
                int i = ilo + r;
                if (jok && i <= ihi) {
                    // 64 lanes -> 64 consecutive floats: 2 lanes/bank (free)
                    __hip_atomic_fetch_add(&tile[i][j - j0],
                                           gkern(w1 - (float)i) * ej,
                                           __ATOMIC_RELAXED,
                                           __HIP_MEMORY_SCOPE_WORKGROUP);
                }
                i += 8;                            // window is <= 11 rows
                if (jok && r < 3 && i <= ihi) {
                    __hip_atomic_fetch_add(&tile[i][j - j0],
                                           gkern(w1 - (float)i) * ej,
                                           __ATOMIC_RELAXED,
                                           __HIP_MEMORY_SCOPE_WORKGROUP);
                }
            }
        }
    }
    __syncthreads();

    // ---- flush partial tile into global joint (skip exact zeros) ---------
    float* jb = joint + b * (NB * NB);
    #pragma unroll
    for (int k = 0; k < NB * JW / 256; ++k) {                   // 8 iters
        int idx = k * 256 + tid;
        int i   = idx >> 3;
        int jj  = idx & 7;
        float val = tf[idx];
        if (val != 0.0f)
            __hip_atomic_fetch_add(&jb[i * NB + j0 + jj], val,
                                   __ATOMIC_RELAXED, __HIP_MEMORY_SCOPE_AGENT);
    }
}

// ---------------------------------------------------------------------------
static __device__ __forceinline__ float block_sum1024(float v, float* scratch) {
    const int lane = threadIdx.x & 63;
    const int wid  = threadIdx.x >> 6;     // 0..15
    #pragma unroll
    for (int off = 32; off > 0; off >>= 1) v += __shfl_down(v, off);
    __syncthreads();                       // protect scratch from previous use
    if (lane == 0) scratch[wid] = v;
    __syncthreads();
    float s = 0.0f;
    #pragma unroll
    for (int w = 0; w < 16; ++w) s += scratch[w];
    return s;
}

__global__ __launch_bounds__(1024)
void mi_final_kernel(const float* __restrict__ hist,
                     const float* __restrict__ joint,
                     float* __restrict__ out) {
    const int b   = blockIdx.x;            // 8 blocks
    const int tid = threadIdx.x;           // 0..1023
    __shared__ float scratch[16];

    float h1 = 0.0f, h2 = 0.0f;
    if (tid < NB) {
        h1 = hist[b * NB + tid] * (1.0f / (float)NSAMP);
        h2 = hist[(4 + (b & 3)) * NB + tid] * (1.0f / (float)NSAMP);
    }
    float n1 = block_sum1024(h1, scratch) + EPSV;
    float n2 = block_sum1024(h2, scratch) + EPSV;
    float p1 = (tid < NB) ? h1 / n1 : 0.0f;
    float p2 = (tid < NB) ? h2 / n2 : 0.0f;
    float e1 = (tid < NB) ? p1 * log2f(p1 + EPSV) : 0.0f;
    float e2 = (tid < NB) ? p2 * log2f(p2 + EPSV) : 0.0f;
    float Hx1 = -block_sum1024(e1, scratch);
    float Hx2 = -block_sum1024(e2, scratch);

    // joint: single pass computing S = sum v and L = sum v*log2 v
    const float4* jb4 = reinterpret_cast<const float4*>(joint + b * (NB * NB));
    float s = 0.0f, l = 0.0f;
    #pragma unroll
    for (int k = 0; k < (NB * NB / 4) / 1024; ++k) {            // 16 iters
        float4 v4 = jb4[k * 1024 + tid];
        #pragma unroll
        for (int e = 0; e < 4; ++e) {
            float v = comp4(v4, e);
            if (v > 0.0f) { s += v; l += v * log2f(v); }
        }
    }
    float Sj = block_sum1024(s, scratch);
    float Lj = block_sum1024(l, scratch);

    if (tid == 0) {
        float Sp = Sj + EPSV;
        float Hj = log2f(Sp) * (Sj / Sp) - Lj / Sp;
        float mi = Hx1 + Hx2 - Hj;
        out[b] = 2.0f * mi / (Hx1 + Hx2);
    }
}

// ---------------------------------------------------------------------------
extern "C" void kernel_launch(void* const* d_in, const int* in_sizes, int n_in,
                              void* d_out, int out_size, void* d_ws, size_t ws_size,
                              hipStream_t stream) {
    const float* in1 = (const float*)d_in[0];
    const float* in2 = (const float*)d_in[1];
    // d_in[2] = bins: linspace(0,255,256); bins[i] == (float)i exactly.
    float* out   = (float*)d_out;
    float* hist  = (float*)d_ws;                   // [8][256]
    float* joint = hist + NROWS * NB;              // [8][256][256]

    const size_t nz_bytes = (size_t)(NROWS * NB + NROWS * NB * NB) * sizeof(float);
    hipMemsetAsync(d_ws, 0, nz_bytes, stream);     // graph-capture-safe

    mi_main_kernel<<<NBLK_ALL, 256, 0, stream>>>(in1, in2, hist, joint);

    mi_final_kernel<<<NROWS, 1024, 0, stream>>>(hist, joint, out);
}

// Round 10
// 120.298 us; speedup vs baseline: 1.1385x; 1.1385x over previous
//
#include <hip/hip_runtime.h>
#include <hip/hip_bf16.h>
#include <math.h>

// Problem constants (fixed by setup_inputs): B=4, C=1, H=W=256 -> N=65536/row,
// concat doubles batch to 8 rows. bins = linspace(0,255,256) -> bins[i] == i
// exactly in f32. Values are uniform[0,1)*1275.
//
// exp(-0.5*((v-i)/0.32)^2) == 0.0f for |v-i| > ~4.61 (f32 underflow), so a
// radius-5 window is numerically identical to the dense reference (verified:
// absmax == 0.0 in rounds 4 and 6).
//
// Joint entropy via H = log2(S')*(S/S') - (sum v*log2 v)/S', S' = S + EPS
// (verified exact in rounds 4/6).
//
// Round-10 design (round-6 counters: main 62us @ VALUBusy 31%, final 120us @
// 8 blocks reading 2MB atomically-merged joint):
//  (a) joint tiles fully block-owned -> no global joint, no memset, final
//      kernel reads only 130KB;
//  (b) event stamping wave-parallel: ballot-compact into per-wave LDS ring
//      queues, process 8 events x 8 j-lanes per stamp, 11-cell i-loop with
//      log2-domain quadratic recurrence (2 adds + exp2 + ds_add per cell);
//  (c) 1024 threads/block (16 waves/CU = 50% occupancy; grid is pinned at
//      256 = 1 block/CU by tile ownership) and per-ballot queue drain
//      (max ring occupancy 71 -> QCAP 128, queues 16KB).
#define NB     256
#define NSAMP  65536
#define NROWS  8
#define RADIUS 5.0f
#define EPSV   1e-10f

#define NT     1024       // threads per block
#define NW     (NT / 64)  // 16 waves
#define JW     8          // joint j-tile width
#define NJT    32         // j tiles; grid = 8 batches * 32 = 256 blocks
#define NHCH   16         // hist chunks per row (4096 samples); 8*16=128 jobs
#define QCAP   128        // per-wave event ring capacity (power of 2)
#define QMASK  (QCAP - 1)

// exp(-0.5*(d/0.32)^2) = exp2(EC * d * d), EC = -0.5*log2(e)/0.1024
#define EC     (-7.0444093793406415f)
#define TWO_EC (2.0f * EC)

static __device__ __forceinline__ float scale_val(float x) {
    return x * 255.0f * 5.0f;   // match reference assoc: (x*255)*5
}
static __device__ __forceinline__ float comp4(const float4& v, int e) {
    return e == 0 ? v.x : e == 1 ? v.y : e == 2 ? v.z : v.w;
}
static __device__ __forceinline__ int prefix_count(unsigned long long m) {
    // number of set bits in m strictly below this lane
    return __builtin_amdgcn_mbcnt_hi((unsigned)(m >> 32),
           __builtin_amdgcn_mbcnt_lo((unsigned)m, 0));
}

// ---------------------------------------------------------------------------
// Stamp 8 queued events with one wave: lane = 8*event_slot + j_offset.
// Each lane owns one j-column of its event's <=11x<=8 Gaussian window and
// walks i with the exact quadratic recurrence l_k = EC*((d0-k)^2 + dj^2):
//   l += dl; dl += 2*EC   (dl_0 = EC*(1-2*d0))
// TWO=false: v1 == v2 stream, queue stores only v2. Tail lanes (e >= cnt)
// may read uninitialized LDS; every store is gated by jok (includes eok).
template<bool TWO>
__device__ __forceinline__ void stamp8(float* __restrict__ tile,
                                       const float* __restrict__ qv1,
                                       const float* __restrict__ qv2,
                                       int head, int cnt, int j0, int lane) {
    const int  e   = head + (lane >> 3);
    const int  u   = lane & 7;
    const bool eok = e < cnt;
    const float w2 = qv2[e & QMASK];
    const float w1 = TWO ? qv1[e & QMASK] : w2;
    int jlo = (int)ceilf(w2 - RADIUS);  if (jlo < j0) jlo = j0;
    int jhi = (int)floorf(w2 + RADIUS); { int jm = j0 + JW - 1; if (jhi > jm) jhi = jm; }
    const int  j   = jlo + u;
    const bool jok = eok && (j <= jhi);
    int ilo = (int)ceilf(w1 - RADIUS);  if (ilo < 0)   ilo = 0;
    int ihi = (int)floorf(w1 + RADIUS); if (ihi > 255) ihi = 255;
    const int ni = ihi - ilo;              // <= 10; negative -> no stores
    const float dj = w2 - (float)j;
    const float d0 = w1 - (float)ilo;
    float l  = EC * d0 * d0 + EC * dj * dj;
    float dl = EC * (1.0f - 2.0f * d0);
    int addr = ilo * JW + (j - j0);
    #pragma unroll
    for (int k = 0; k < 11; ++k) {
        if (jok && k <= ni)
            __hip_atomic_fetch_add(&tile[addr], exp2f(l), __ATOMIC_RELAXED,
                                   __HIP_MEMORY_SCOPE_WORKGROUP);
        l += dl; dl += TWO_EC; addr += JW;
    }
}

// ---------------------------------------------------------------------------
// Scan this block's full sample stream; ballot-compact events into the
// per-wave ring queue; drain in groups of 8 after every ballot (max ring
// occupancy 7 + 64 = 71 < QCAP). TWO: v1 independent stream (b<4).
template<bool TWO>
__device__ __forceinline__ void joint_scan(const float* __restrict__ s1,
                                           const float* __restrict__ s2,
                                           float* __restrict__ tile,
                                           float* __restrict__ qv1,
                                           float* __restrict__ qv2,
                                           int j0, int tid, int lane) {
    const float jlof  = (float)j0 - RADIUS;
    const float jhif  = (float)(j0 + JW - 1) + RADIUS;
    const float v1max = 255.0f + RADIUS;
    const float4* s24 = reinterpret_cast<const float4*>(s2);
    const float4* s14 = reinterpret_cast<const float4*>(s1);
    int cnt = 0, head = 0;                 // wave-uniform by construction
    for (int k = 0; k < NSAMP / (NT * 4); ++k) {       // 16 iters
        const float4 c2v = s24[k * NT + tid];
        float4 c1v;
        if (TWO) c1v = s14[k * NT + tid];
        #pragma unroll
        for (int e = 0; e < 4; ++e) {
            const float v2 = scale_val(comp4(c2v, e));
            const float v1 = TWO ? scale_val(comp4(c1v, e)) : v2;
            bool pass = (v2 >= jlof) && (v2 <= jhif);
            if (TWO) pass = pass && (v1 <= v1max);
            const unsigned long long m = __ballot(pass);
            if (pass) {
                const int slot = (cnt + prefix_count(m)) & QMASK;
                if (TWO) qv1[slot] = v1;   // per-wave queue: no atomics, no
                qv2[slot] = v2;            // sync (in-order LDS pipe per wave)
            }
            cnt += (int)__popcll(m);
            while (cnt - head >= 8) {
                stamp8<TWO>(tile, qv1, qv2, head, cnt, j0, lane);
                head += 8;
            }
        }
    }
    if (cnt > head) stamp8<TWO>(tile, qv1, qv2, head, cnt, j0, lane);
}

// ---------------------------------------------------------------------------
// Grid 256 blocks x 1024 threads: block (b, jt) owns joint[b][:, jt*8..+8)
// completely (scans all samples) -> direct (S,L) output, no global joint.
// b<4 blocks (x in [0,128)) additionally compute hist chunk x&15 of row x>>4.
__global__ __launch_bounds__(NT, 4)
void mi_main_kernel(const float* __restrict__ in1,
                    const float* __restrict__ in2,
                    float* __restrict__ hist_part,   // [8][16][256]
                    float* __restrict__ jpart) {     // [8][32][2]
    const int x    = blockIdx.x;           // 0..255
    const int b    = x >> 5;               // 0..7
    const int jt   = x & 31;
    const int tid  = threadIdx.x;          // 0..1023
    const int lane = tid & 63;
    const int wid  = tid >> 6;             // 0..15

    __shared__ float tile[NB * JW];        // 8 KiB joint tile
    __shared__ float sh[NB];               // 1 KiB hist partial
    __shared__ float q1[NW * QCAP];        // 8 KiB per-wave v1 rings
    __shared__ float q2[NW * QCAP];        // 8 KiB per-wave v2 rings
    __shared__ float scr_s[NW], scr_l[NW];

    #pragma unroll
    for (int k = 0; k < NB * JW / NT; ++k) tile[k * NT + tid] = 0.0f;
    if (tid < NB) sh[tid] = 0.0f;
    __syncthreads();

    const float* s2 = in2 + (b & 3) * NSAMP;
    const float* s1 = (b < 4) ? (in1 + b * NSAMP) : s2;

    if (b < 4) {
        // ---- hist job: row x>>4, chunk x&15 (4096 samples, 1 float4/thr) --
        const int row = x >> 4;
        const int ch  = x & 15;
        const float* hs = (row < 4) ? (in1 + row * NSAMP)
                                    : (in2 + (row - 4) * NSAMP);
        const float4* h4 =
            reinterpret_cast<const float4*>(hs + ch * (NSAMP / NHCH));
        float4 v4 = h4[tid];
        #pragma unroll
        for (int e = 0; e < 4; ++e) {
            float v = scale_val(comp4(v4, e));
            if (v <= 255.0f + RADIUS) {
                int i0 = (int)ceilf(v - RADIUS);  if (i0 < 0)   i0 = 0;
                int i1 = (int)floorf(v + RADIUS); if (i1 > 255) i1 = 255;
                float d0 = v - (float)i0;
                float l  = EC * d0 * d0;
                float dl = EC * (1.0f - 2.0f * d0);
                for (int i = i0; i <= i1; ++i) {
                    __hip_atomic_fetch_add(&sh[i], exp2f(l), __ATOMIC_RELAXED,
                                           __HIP_MEMORY_SCOPE_WORKGROUP);
                    l += dl; dl += TWO_EC;
                }
            }
        }
    }

    // ---- joint scan + stamp ----------------------------------------------
    const int j0 = jt * JW;
    float* qv1 = q1 + wid * QCAP;
    float* qv2 = q2 + wid * QCAP;
    if (b < 4) joint_scan<true >(s1, s2, tile, qv1, qv2, j0, tid, lane);
    else       joint_scan<false>(s1, s2, tile, qv1, qv2, j0, tid, lane);

    __syncthreads();

    if (b < 4 && tid < NB) {
        const int row = x >> 4, ch = x & 15;
        hist_part[(row * NHCH + ch) * NB + tid] = sh[tid];
    }

    // ---- reduce tile -> (sum v, sum v*log2 v); exclusive store -----------
    float s = 0.0f, l = 0.0f;
    #pragma unroll
    for (int k = 0; k < NB * JW / NT; ++k) {           // 2 iters
        float v = tile[k * NT + tid];
        if (v > 0.0f) { s += v; l += v * log2f(v); }
    }
    #pragma unroll
    for (int off = 32; off > 0; off >>= 1) {
        s += __shfl_down(s, off);
        l += __shfl_down(l, off);
    }
    if (lane == 0) { scr_s[wid] = s; scr_l[wid] = l; }
    __syncthreads();
    if (tid == 0) {
        float S = 0.0f, L = 0.0f;
        #pragma unroll
        for (int w = 0; w < NW; ++w) { S += scr_s[w]; L += scr_l[w]; }
        jpart[(b * NJT + jt) * 2 + 0] = S;
        jpart[(b * NJT + jt) * 2 + 1] = L;
    }
}

// ---------------------------------------------------------------------------
static __device__ __forceinline__ float block_sum256(float v, float* scratch) {
    const int lane = threadIdx.x & 63;
    const int wid  = threadIdx.x >> 6;     // 0..3
    #pragma unroll
    for (int off = 32; off > 0; off >>= 1) v += __shfl_down(v, off);
    __syncthreads();                       // protect scratch from previous use
    if (lane == 0) scratch[wid] = v;
    __syncthreads();
    return scratch[0] + scratch[1] + scratch[2] + scratch[3];
}

__global__ __launch_bounds__(256)
void mi_final_kernel(const float* __restrict__ hist_part,
                     const float* __restrict__ jpart,
                     float* __restrict__ out) {
    const int b   = blockIdx.x;            // 8 blocks
    const int tid = threadIdx.x;           // 0..255, one bin each
    __shared__ float scratch[4];

    float h1 = 0.0f, h2 = 0.0f;
    #pragma unroll
    for (int c = 0; c < NHCH; ++c) {
        h1 += hist_part[(b * NHCH + c) * NB + tid];
        h2 += hist_part[((4 + (b & 3)) * NHCH + c) * NB + tid];
    }
    h1 *= (1.0f / (float)NSAMP);           // pdf = mean over N
    h2 *= (1.0f / (float)NSAMP);
    float n1 = block_sum256(h1, scratch) + EPSV;
    float n2 = block_sum256(h2, scratch) + EPSV;
    float p1 = h1 / n1;
    float p2 = h2 / n2;
    float Hx1 = -block_sum256(p1 * log2f(p1 + EPSV), scratch);
    float Hx2 = -block_sum256(p2 * log2f(p2 + EPSV), scratch);

    float sp = 0.0f, lp = 0.0f;
    if (tid < NJT) {
        sp = jpart[(b * NJT + tid) * 2 + 0];
        lp = jpart[(b * NJT + tid) * 2 + 1];
    }
    float Sj = block_sum256(sp, scratch);
    float Lj = block_sum256(lp, scratch);

    if (tid == 0) {
        float Sp = Sj + EPSV;
        float Hj = log2f(Sp) * (Sj / Sp) - Lj / Sp;
        float mi = Hx1 + Hx2 - Hj;
        out[b] = 2.0f * mi / (Hx1 + Hx2);
    }
}

// ---------------------------------------------------------------------------
extern "C" void kernel_launch(void* const* d_in, const int* in_sizes, int n_in,
                              void* d_out, int out_size, void* d_ws, size_t ws_size,
                              hipStream_t stream) {
    const float* in1 = (const float*)d_in[0];
    const float* in2 = (const float*)d_in[1];
    // d_in[2] = bins: linspace(0,255,256); bins[i] == (float)i exactly.
    float* out       = (float*)d_out;
    float* hist_part = (float*)d_ws;                       // 8*16*256 f32 (128 KB)
    float* jpart     = hist_part + NROWS * NHCH * NB;      // 8*32*2 f32

    mi_main_kernel<<<NROWS * NJT, NT, 0, stream>>>(in1, in2, hist_part, jpart);

    mi_final_kernel<<<NROWS, 256, 0, stream>>>(hist_part, jpart, out);
}